// Round 3
// baseline (403.068 us; speedup 1.0000x reference)
//
#include <hip/hip_runtime.h>
#include <cstdint>
#include <cstddef>

// Problem constants
constexpr int T_N = 8192;   // rows of x / out
constexpr int MM  = 4096;   // K (cols of x, cols of W)
constexpr int NN  = 4096;   // rows of W / cols of out
constexpr int S_L = 2048;
constexpr int S_R = 2048;
constexpr float EPS_ = 1e-6f;

typedef float  f32x4  __attribute__((ext_vector_type(4)));
typedef __bf16 bf16x8 __attribute__((ext_vector_type(8)));
typedef unsigned short ushort8 __attribute__((ext_vector_type(8)));

__device__ __forceinline__ unsigned short f2bf(float f) {
  unsigned int u = __float_as_uint(f);
  u += 0x7FFFu + ((u >> 16) & 1u);   // round-to-nearest-even
  return (unsigned short)(u >> 16);
}

// ---------------------------------------------------------------------------
// Kernel 1: default maps (identity)
// ---------------------------------------------------------------------------
__global__ void init_maps(float* rowC, float* rowS, int* rowP,
                          float* colC, float* colS, int* colP) {
  int i = blockIdx.x * blockDim.x + threadIdx.x;
  if (i < NN) { rowC[i] = 1.f; rowS[i] = 0.f; rowP[i] = i; }
  if (i < MM) { colC[i] = 1.f; colS[i] = 0.f; colP[i] = i; }
}

// ---------------------------------------------------------------------------
// Kernel 2: per-index rotation maps from (pairs, theta).
// ---------------------------------------------------------------------------
__global__ void build_maps(const float* __restrict__ thL, const float* __restrict__ thR,
                           const int* __restrict__ prL, const int* __restrict__ prR,
                           float* rowC, float* rowS, int* rowP,
                           float* colC, float* colS, int* colP) {
  int s = blockIdx.x * blockDim.x + threadIdx.x;
  if (s < S_L) {
    int i = prL[2*s], j = prL[2*s+1];
    float c = cosf(thL[s]), sn = sinf(thL[s]);
    rowC[i] = c; rowS[i] = -sn; rowP[i] = j;
    rowC[j] = c; rowS[j] =  sn; rowP[j] = i;
  }
  if (s < S_R) {
    int i = prR[2*s], j = prR[2*s+1];
    float c = cosf(thR[s]), sn = sinf(thR[s]);
    colC[i] = c; colS[i] = -sn; colP[i] = j;
    colC[j] = c; colS[j] =  sn; colP[j] = i;
  }
}

// ---------------------------------------------------------------------------
// Kernel 3: build W_eff row-by-row, fused row-norm, emit bf16.
// ---------------------------------------------------------------------------
__global__ __launch_bounds__(256) void build_weff(
    const float* __restrict__ W, const float* __restrict__ brn, const float* __restrict__ elm,
    const float* __restrict__ rowC, const float* __restrict__ rowS, const int* __restrict__ rowP,
    const float* __restrict__ colC, const float* __restrict__ colS, const int* __restrict__ colP,
    unsigned short* __restrict__ Wb)
{
  __shared__ __align__(16) float rA[MM];
  __shared__ __align__(16) float rB[MM];
  __shared__ __align__(16) float rE[MM];
  __shared__ float red[4];

  int n   = blockIdx.x;
  int tid = threadIdx.x;
  int pn  = rowP[n];
  float cl = rowC[n], sl = rowS[n];
  const float* Wn = W + (size_t)n  * MM;
  const float* Wp = W + (size_t)pn * MM;

  for (int m = tid * 4; m < MM; m += 1024) {
    *(f32x4*)&rA[m] = *(const f32x4*)&Wn[m];
    *(f32x4*)&rB[m] = *(const f32x4*)&Wp[m];
  }
  __syncthreads();

  float ss = 0.f;
  for (int m = tid; m < MM; m += 256) {
    int p = colP[m];
    float c = colC[m], s = colS[m];
    float e = cl * (c * rA[m] + s * rA[p]) + sl * (c * rB[m] + s * rB[p]);
    rE[m] = e;
    ss += e * e;
  }
  #pragma unroll
  for (int o = 32; o; o >>= 1) ss += __shfl_xor(ss, o);
  int lane = tid & 63, wid = tid >> 6;
  if (lane == 0) red[wid] = ss;
  __syncthreads();
  float tot = red[0] + red[1] + red[2] + red[3];
  float scale = brn[n] * expf(elm[n]) / sqrtf(tot + EPS_);

  for (int m = tid * 8; m < MM; m += 2048) {
    ushort8 pkt;
    #pragma unroll
    for (int q = 0; q < 8; q++) pkt[q] = f2bf(rE[m + q] * scale);
    *(ushort8*)&Wb[(size_t)n * MM + m] = pkt;
  }
}

// ---------------------------------------------------------------------------
// Kernel 4: x (f32) -> bf16
// ---------------------------------------------------------------------------
__global__ __launch_bounds__(256) void conv_x(const float* __restrict__ x,
                                              unsigned short* __restrict__ xb) {
  const size_t total = (size_t)T_N * MM / 8;
  for (size_t i = (size_t)blockIdx.x * 256 + threadIdx.x; i < total; i += 2048ull * 256ull) {
    const float* s = x + i * 8;
    f32x4 v0 = *(const f32x4*)s;
    f32x4 v1 = *(const f32x4*)(s + 4);
    ushort8 p;
    p[0] = f2bf(v0.x); p[1] = f2bf(v0.y); p[2] = f2bf(v0.z); p[3] = f2bf(v0.w);
    p[4] = f2bf(v1.x); p[5] = f2bf(v1.y); p[6] = f2bf(v1.z); p[7] = f2bf(v1.w);
    *(ushort8*)(xb + i * 8) = p;
  }
}

// ---------------------------------------------------------------------------
// global->LDS async staging helper (16B, linear LDS dest)
// ---------------------------------------------------------------------------
typedef const __attribute__((address_space(1))) unsigned int* as1_u32p;
typedef __attribute__((address_space(3))) unsigned int* as3_u32p;

__device__ __forceinline__ void gl_lds16(const void* g, void* l) {
  __builtin_amdgcn_global_load_lds((as1_u32p)g, (as3_u32p)l, 16, 0, 0);
}

// ---------------------------------------------------------------------------
// Kernel 5a: 256x256 deep-pipelined GEMM  C[T][N] = A[T][M]*B[N][M]^T + bias
//   bf16 MFMA 16x16x32, 8 waves (2Mx4N), per-wave 128x64, acc[8][4].
//   BK=32, 4 LDS buffers (4 x 32 KiB), staging 3 K-tiles ahead.
//   Steady state: vmcnt(8) gate (2 tiles in flight) -> never drains to 0.
//   1 barrier + 1 vmcnt + 1 lgkmcnt per K-tile.
//   Swizzle: 64B rows, colu ^= (row>>1)&3 on both write-src and read (2-way,
//   free). T5 setprio around the 32-MFMA cluster.
// ---------------------------------------------------------------------------
constexpr int GBM = 256, GBN = 256, GBK = 32;
constexpr int NT2 = MM / GBK;           // 128 K-tiles
constexpr int BUFE = GBM * GBK;         // 8192 elements per buffer (16 KiB)

__global__ __launch_bounds__(512, 2) void gemm8(
    const unsigned short* __restrict__ xb,
    const unsigned short* __restrict__ wb,
    const float* __restrict__ bias,
    float* __restrict__ C)
{
  __shared__ __align__(16) unsigned short As[4 * BUFE];  // 64 KiB
  __shared__ __align__(16) unsigned short Bs[4 * BUFE];  // 64 KiB
  char* ldsA = (char*)As;
  char* ldsB = (char*)Bs;

  // grid = 512 = 32 (tm) x 16 (tn); 512 % 8 == 0 -> simple XCD swizzle
  int bid = blockIdx.x;
  int swz = (bid & 7) * 64 + (bid >> 3);
  int tn = swz & 15, tm = swz >> 4;
  const int trow0 = tm * GBM;
  const int tcol0 = tn * GBN;

  int tid  = threadIdx.x;
  int lane = tid & 63;
  int wid  = tid >> 6;
  int wr = wid >> 2, wc = wid & 3;   // wave coords: 2 x 4
  int lr = lane & 15;                // fragment row/col
  int lg = lane >> 4;                // k-group (8 bf16 = 16B)

  // ---- per-thread staging geometry: rows of 32 elems = 4 x 16B slots ----
  // off16 unit u -> row = u>>2, colu = u&3; source col-group = colu ^ ((row>>1)&3)
  int u0 = tid, u1 = 512 + tid;
  int r0s = u0 >> 2, c0s = u0 & 3;
  int r1s = u1 >> 2, c1s = u1 & 3;
  const unsigned short* srcA0 = xb + (size_t)(trow0 + r0s) * MM + ((c0s ^ ((r0s >> 1) & 3)) << 3);
  const unsigned short* srcA1 = xb + (size_t)(trow0 + r1s) * MM + ((c1s ^ ((r1s >> 1) & 3)) << 3);
  const unsigned short* srcB0 = wb + (size_t)(tcol0 + r0s) * MM + ((c0s ^ ((r0s >> 1) & 3)) << 3);
  const unsigned short* srcB1 = wb + (size_t)(tcol0 + r1s) * MM + ((c1s ^ ((r1s >> 1) & 3)) << 3);
  const int dst0 = u0 * 16;   // byte offset within buffer
  const int dst1 = u1 * 16;

  // ---- per-lane fragment byte offsets within a buffer (swizzled) ----
  int aoff[8], boff[4];
  #pragma unroll
  for (int mi = 0; mi < 8; ++mi) {
    int r = wr * 128 + mi * 16 + lr;
    aoff[mi] = r * 64 + ((lg ^ ((r >> 1) & 3)) << 4);
  }
  #pragma unroll
  for (int ni = 0; ni < 4; ++ni) {
    int r = wc * 64 + ni * 16 + lr;
    boff[ni] = r * 64 + ((lg ^ ((r >> 1) & 3)) << 4);
  }

  f32x4 acc[8][4];
  #pragma unroll
  for (int i = 0; i < 8; i++)
    #pragma unroll
    for (int j = 0; j < 4; j++) {
      f32x4 z = {0.f, 0.f, 0.f, 0.f};
      acc[i][j] = z;
    }

  // ---- prologue: stage tiles 0,1,2 into buffers 0,1,2 (12 loads/thread) ----
  #pragma unroll
  for (int p = 0; p < 3; ++p) {
    const int kof = p * GBK;
    const int bb  = p * (BUFE * 2);     // buffer byte base
    gl_lds16(srcA0 + kof, ldsA + bb + dst0);
    gl_lds16(srcA1 + kof, ldsA + bb + dst1);
    gl_lds16(srcB0 + kof, ldsB + bb + dst0);
    gl_lds16(srcB1 + kof, ldsB + bb + dst1);
  }

  // ---- main loop: 1 barrier + 1 counted-vmcnt + 1 lgkmcnt per K-tile ----
#define TILE_BODY(T, VMC)                                                     \
  {                                                                           \
    const int t_ = (T);                                                       \
    asm volatile("s_waitcnt vmcnt(" #VMC ")" ::: "memory");                   \
    __builtin_amdgcn_s_barrier();                                             \
    if (t_ + 3 < NT2) {                                                       \
      const int kof = (t_ + 3) * GBK;                                         \
      const int bb  = ((t_ + 3) & 3) * (BUFE * 2);                            \
      gl_lds16(srcA0 + kof, ldsA + bb + dst0);                                \
      gl_lds16(srcA1 + kof, ldsA + bb + dst1);                                \
      gl_lds16(srcB0 + kof, ldsB + bb + dst0);                                \
      gl_lds16(srcB1 + kof, ldsB + bb + dst1);                                \
    }                                                                         \
    const char* Ab = ldsA + (t_ & 3) * (BUFE * 2);                            \
    const char* Bb = ldsB + (t_ & 3) * (BUFE * 2);                            \
    bf16x8 bf[4], af[8];                                                      \
    _Pragma("unroll")                                                         \
    for (int ni = 0; ni < 4; ++ni) bf[ni] = *(const bf16x8*)(Bb + boff[ni]);  \
    _Pragma("unroll")                                                         \
    for (int mi = 0; mi < 8; ++mi) af[mi] = *(const bf16x8*)(Ab + aoff[mi]);  \
    asm volatile("s_waitcnt lgkmcnt(0)" ::: "memory");                        \
    __builtin_amdgcn_sched_barrier(0);                                        \
    __builtin_amdgcn_s_setprio(1);                                            \
    _Pragma("unroll")                                                         \
    for (int mi = 0; mi < 8; ++mi)                                            \
      _Pragma("unroll")                                                       \
      for (int ni = 0; ni < 4; ++ni)                                          \
        acc[mi][ni] = __builtin_amdgcn_mfma_f32_16x16x32_bf16(                \
            af[mi], bf[ni], acc[mi][ni], 0, 0, 0);                            \
    __builtin_amdgcn_s_setprio(0);                                            \
  }

  for (int t = 0; t < NT2 - 2; ++t) TILE_BODY(t, 8)
  TILE_BODY(NT2 - 2, 4)
  TILE_BODY(NT2 - 1, 0)
#undef TILE_BODY

  // ---- epilogue: C/D layout col = lane&15, row = (lane>>4)*4 + reg ----
  #pragma unroll
  for (int ni = 0; ni < 4; ++ni) {
    int col = tcol0 + wc * 64 + ni * 16 + lr;
    float bi = bias[col];
    #pragma unroll
    for (int mi = 0; mi < 8; ++mi) {
      int rr0 = trow0 + wr * 128 + mi * 16 + lg * 4;
      #pragma unroll
      for (int qq = 0; qq < 4; ++qq)
        C[(size_t)(rr0 + qq) * NN + col] = acc[mi][ni][qq] + bi;
    }
  }
}

// ---------------------------------------------------------------------------
// Kernel 5b (fallback, ws too small for xb): m97-style 128x128 GEMM with
// inline f32->bf16 A-staging.
// ---------------------------------------------------------------------------
constexpr int BM = 128, BN = 128, BK = 64;

__global__ __launch_bounds__(256) void gemm_fb(
    const float* __restrict__ xf,
    const unsigned short* __restrict__ wb, const float* __restrict__ bias,
    float* __restrict__ C)
{
  __shared__ __align__(16) unsigned short As[BM * BK];
  __shared__ __align__(16) unsigned short Bs[BN * BK];

  int bid = blockIdx.x;
  int swz = (bid & 7) * 256 + (bid >> 3);
  int tn = swz & 31;
  int tm = swz >> 5;

  int tid  = threadIdx.x;
  int lane = tid & 63;
  int wid  = tid >> 6;
  int wr = wid >> 1, wc = wid & 1;
  int lr = lane & 15;
  int lg = lane >> 4;

  f32x4 acc[4][4];
  #pragma unroll
  for (int i = 0; i < 4; i++)
    #pragma unroll
    for (int j = 0; j < 4; j++) {
      f32x4 z = {0.f, 0.f, 0.f, 0.f};
      acc[i][j] = z;
    }

  int srow = tid >> 3;
  int scol = (tid & 7) * 8;
  const size_t a_base = (size_t)(tm * BM) * MM;
  const size_t b_base = (size_t)(tn * BN) * MM;

  for (int k0 = 0; k0 < MM; k0 += BK) {
    #pragma unroll
    for (int c = 0; c < 4; c++) {
      int row = c * 32 + srow;
      gl_lds16(wb + b_base + (size_t)row * MM + k0 + scol,
               (char*)Bs + (c * 256 + wid * 64) * 16);
    }
    #pragma unroll
    for (int c = 0; c < 4; c++) {
      int row = c * 32 + srow;
      const float* s = xf + a_base + (size_t)row * MM + k0 + scol;
      f32x4 v0 = *(const f32x4*)s;
      f32x4 v1 = *(const f32x4*)(s + 4);
      ushort8 p;
      p[0] = f2bf(v0.x); p[1] = f2bf(v0.y); p[2] = f2bf(v0.z); p[3] = f2bf(v0.w);
      p[4] = f2bf(v1.x); p[5] = f2bf(v1.y); p[6] = f2bf(v1.z); p[7] = f2bf(v1.w);
      *(ushort8*)&As[(c * 256 + tid) * 8] = p;
    }
    __syncthreads();

    #pragma unroll
    for (int kk = 0; kk < 2; kk++) {
      bf16x8 a[4], b[4];
      #pragma unroll
      for (int i = 0; i < 4; i++) {
        a[i] = *(const bf16x8*)&As[(wr * 64 + i * 16 + lr) * BK + kk * 32 + lg * 8];
        b[i] = *(const bf16x8*)&Bs[(wc * 64 + i * 16 + lr) * BK + kk * 32 + lg * 8];
      }
      #pragma unroll
      for (int i = 0; i < 4; i++)
        #pragma unroll
        for (int j = 0; j < 4; j++)
          acc[i][j] = __builtin_amdgcn_mfma_f32_16x16x32_bf16(a[i], b[j], acc[i][j], 0, 0, 0);
    }
    __syncthreads();
  }

  int gn0 = tn * BN + wc * 64;
  int gt0 = tm * BM + wr * 64;
  #pragma unroll
  for (int j = 0; j < 4; j++) {
    int gn = gn0 + j * 16 + lr;
    float bi = bias[gn];
    #pragma unroll
    for (int i = 0; i < 4; i++) {
      int t0 = gt0 + i * 16 + lg * 4;
      #pragma unroll
      for (int q = 0; q < 4; q++)
        C[(size_t)(t0 + q) * NN + gn] = acc[i][j][q] + bi;
    }
  }
}

// ---------------------------------------------------------------------------
extern "C" void kernel_launch(void* const* d_in, const int* in_sizes, int n_in,
                              void* d_out, int out_size, void* d_ws, size_t ws_size,
                              hipStream_t stream)
{
  const float* x    = (const float*)d_in[0];
  const float* W    = (const float*)d_in[1];
  const float* bias = (const float*)d_in[2];
  const float* thL  = (const float*)d_in[3];
  const float* thR  = (const float*)d_in[4];
  const float* elm  = (const float*)d_in[5];
  const float* brn  = (const float*)d_in[6];
  const int*   prL  = (const int*)d_in[7];
  const int*   prR  = (const int*)d_in[8];
  float* out = (float*)d_out;

  char* ws = (char*)d_ws;
  unsigned short* Wb = (unsigned short*)ws;          // N*M bf16 = 33.5 MB
  size_t off = (size_t)NN * MM * 2;
  float* rowC = (float*)(ws + off); off += NN * 4;
  float* rowS = (float*)(ws + off); off += NN * 4;
  int*   rowP = (int*)  (ws + off); off += NN * 4;
  float* colC = (float*)(ws + off); off += MM * 4;
  float* colS = (float*)(ws + off); off += MM * 4;
  int*   colP = (int*)  (ws + off); off += MM * 4;
  unsigned short* xb = (unsigned short*)(ws + off);  // T*M bf16 = 67 MB
  bool use_xb = ws_size >= off + (size_t)T_N * MM * 2;

  init_maps <<<16, 256, 0, stream>>>(rowC, rowS, rowP, colC, colS, colP);
  build_maps<<< 8, 256, 0, stream>>>(thL, thR, prL, prR, rowC, rowS, rowP, colC, colS, colP);
  build_weff<<<NN, 256, 0, stream>>>(W, brn, elm, rowC, rowS, rowP, colC, colS, colP, Wb);

  if (use_xb) {
    conv_x<<<2048, 256, 0, stream>>>(x, xb);
    gemm8<<<512, 512, 0, stream>>>(xb, Wb, bias, out);
  } else {
    gemm_fb<<<2048, 256, 0, stream>>>(x, Wb, bias, out);
  }
}

// Round 4
// 354.538 us; speedup vs baseline: 1.1369x; 1.1369x over previous
//
#include <hip/hip_runtime.h>
#include <cstdint>
#include <cstddef>

// Problem constants
constexpr int T_N = 8192;   // rows of x / out
constexpr int MM  = 4096;   // K (cols of x, cols of W)
constexpr int NN  = 4096;   // rows of W / cols of out
constexpr int S_L = 2048;
constexpr int S_R = 2048;
constexpr float EPS_ = 1e-6f;

typedef float  f32x4  __attribute__((ext_vector_type(4)));
typedef __bf16 bf16x8 __attribute__((ext_vector_type(8)));
typedef unsigned short ushort8 __attribute__((ext_vector_type(8)));

__device__ __forceinline__ unsigned short f2bf(float f) {
  unsigned int u = __float_as_uint(f);
  u += 0x7FFFu + ((u >> 16) & 1u);   // round-to-nearest-even
  return (unsigned short)(u >> 16);
}

// ---------------------------------------------------------------------------
// Kernel 1: default maps (identity)
// ---------------------------------------------------------------------------
__global__ void init_maps(float* rowC, float* rowS, int* rowP,
                          float* colC, float* colS, int* colP) {
  int i = blockIdx.x * blockDim.x + threadIdx.x;
  if (i < NN) { rowC[i] = 1.f; rowS[i] = 0.f; rowP[i] = i; }
  if (i < MM) { colC[i] = 1.f; colS[i] = 0.f; colP[i] = i; }
}

// ---------------------------------------------------------------------------
// Kernel 2: per-index rotation maps from (pairs, theta).
// ---------------------------------------------------------------------------
__global__ void build_maps(const float* __restrict__ thL, const float* __restrict__ thR,
                           const int* __restrict__ prL, const int* __restrict__ prR,
                           float* rowC, float* rowS, int* rowP,
                           float* colC, float* colS, int* colP) {
  int s = blockIdx.x * blockDim.x + threadIdx.x;
  if (s < S_L) {
    int i = prL[2*s], j = prL[2*s+1];
    float c = cosf(thL[s]), sn = sinf(thL[s]);
    rowC[i] = c; rowS[i] = -sn; rowP[i] = j;
    rowC[j] = c; rowS[j] =  sn; rowP[j] = i;
  }
  if (s < S_R) {
    int i = prR[2*s], j = prR[2*s+1];
    float c = cosf(thR[s]), sn = sinf(thR[s]);
    colC[i] = c; colS[i] = -sn; colP[i] = j;
    colC[j] = c; colS[j] =  sn; colP[j] = i;
  }
}

// ---------------------------------------------------------------------------
// Kernel 3: build W_eff row-by-row, fused row-norm, emit bf16.
// ---------------------------------------------------------------------------
__global__ __launch_bounds__(256) void build_weff(
    const float* __restrict__ W, const float* __restrict__ brn, const float* __restrict__ elm,
    const float* __restrict__ rowC, const float* __restrict__ rowS, const int* __restrict__ rowP,
    const float* __restrict__ colC, const float* __restrict__ colS, const int* __restrict__ colP,
    unsigned short* __restrict__ Wb)
{
  __shared__ __align__(16) float rA[MM];
  __shared__ __align__(16) float rB[MM];
  __shared__ __align__(16) float rE[MM];
  __shared__ float red[4];

  int n   = blockIdx.x;
  int tid = threadIdx.x;
  int pn  = rowP[n];
  float cl = rowC[n], sl = rowS[n];
  const float* Wn = W + (size_t)n  * MM;
  const float* Wp = W + (size_t)pn * MM;

  for (int m = tid * 4; m < MM; m += 1024) {
    *(f32x4*)&rA[m] = *(const f32x4*)&Wn[m];
    *(f32x4*)&rB[m] = *(const f32x4*)&Wp[m];
  }
  __syncthreads();

  float ss = 0.f;
  for (int m = tid; m < MM; m += 256) {
    int p = colP[m];
    float c = colC[m], s = colS[m];
    float e = cl * (c * rA[m] + s * rA[p]) + sl * (c * rB[m] + s * rB[p]);
    rE[m] = e;
    ss += e * e;
  }
  #pragma unroll
  for (int o = 32; o; o >>= 1) ss += __shfl_xor(ss, o);
  int lane = tid & 63, wid = tid >> 6;
  if (lane == 0) red[wid] = ss;
  __syncthreads();
  float tot = red[0] + red[1] + red[2] + red[3];
  float scale = brn[n] * expf(elm[n]) / sqrtf(tot + EPS_);

  for (int m = tid * 8; m < MM; m += 2048) {
    ushort8 pkt;
    #pragma unroll
    for (int q = 0; q < 8; q++) pkt[q] = f2bf(rE[m + q] * scale);
    *(ushort8*)&Wb[(size_t)n * MM + m] = pkt;
  }
}

// ---------------------------------------------------------------------------
// Kernel 4: x (f32) -> bf16
// ---------------------------------------------------------------------------
__global__ __launch_bounds__(256) void conv_x(const float* __restrict__ x,
                                              unsigned short* __restrict__ xb) {
  const size_t total = (size_t)T_N * MM / 8;
  for (size_t i = (size_t)blockIdx.x * 256 + threadIdx.x; i < total; i += 2048ull * 256ull) {
    const float* s = x + i * 8;
    f32x4 v0 = *(const f32x4*)s;
    f32x4 v1 = *(const f32x4*)(s + 4);
    ushort8 p;
    p[0] = f2bf(v0.x); p[1] = f2bf(v0.y); p[2] = f2bf(v0.z); p[3] = f2bf(v0.w);
    p[4] = f2bf(v1.x); p[5] = f2bf(v1.y); p[6] = f2bf(v1.z); p[7] = f2bf(v1.w);
    *(ushort8*)(xb + i * 8) = p;
  }
}

// ---------------------------------------------------------------------------
// global->LDS async staging helper (16B, linear LDS dest)
// ---------------------------------------------------------------------------
typedef const __attribute__((address_space(1))) unsigned int* as1_u32p;
typedef __attribute__((address_space(3))) unsigned int* as3_u32p;

__device__ __forceinline__ void gl_lds16(const void* g, void* l) {
  __builtin_amdgcn_global_load_lds((as1_u32p)g, (as3_u32p)l, 16, 0, 0);
}

// ---------------------------------------------------------------------------
// Kernel 5a: 256x256 GEMM, BK=64, 8 waves (2Mx4N), per-wave 128x64, acc[8][4].
// Rolled 4-phase register pipeline with counted lgkmcnt (never 0 mid-tile):
//   p0: STAGE(t+1) | issue af1 | lgkm(4)  | MFMA mi{0,1}   (uses af0_t, B_t)
//   p1:             issue af2 | lgkm(4)  | MFMA mi{2,3}
//   p2: issue af3 | vmcnt(0)+mid-barrier | issue B_{t+1} | lgkm(12) | MFMA mi{4,5}
//   p3: issue af0_{t+1} | lgkm(12) | MFMA mi{6,7}
//   boundary barrier (all tile-t reads complete via p3 gate)
// Swizzle (verified r2): LDS[row][colu]=glob[row][colu^(row&7)] (16B granules);
// read addr: row*128 + ((kk*64+lg*16) ^ ((lr&7)<<4)).  Conflict-free.
// ---------------------------------------------------------------------------
constexpr int GBM = 256, GBN = 256, GBK = 64;
constexpr int NT = MM / GBK;               // 64 K-tiles
constexpr int TILE_BYTES = GBM * GBK * 2;  // 32 KiB per operand per buffer

#define LGKM(N) do { asm volatile("s_waitcnt lgkmcnt(" #N ")" ::: "memory"); \
                     __builtin_amdgcn_sched_barrier(0); } while (0)
#define VMC0()  asm volatile("s_waitcnt vmcnt(0)" ::: "memory")

#define RD_A(DST, AB, Q)                                                      \
  _Pragma("unroll") for (int i_ = 0; i_ < 2; ++i_)                            \
  _Pragma("unroll") for (int kk_ = 0; kk_ < 2; ++kk_)                         \
    DST[i_][kk_] = *(const bf16x8*)((AB) + arow0 + ((Q)*2 + i_) * 2048        \
                                     + ((kk_*64 + lg*16) ^ sw));

#define RD_B(DST, BB)                                                         \
  _Pragma("unroll") for (int ni_ = 0; ni_ < 4; ++ni_)                         \
  _Pragma("unroll") for (int kk_ = 0; kk_ < 2; ++kk_)                         \
    DST[ni_][kk_] = *(const bf16x8*)((BB) + brow0 + ni_ * 2048                \
                                     + ((kk_*64 + lg*16) ^ sw));

#define MFMA_PH(AF, BF, MI0)                                                  \
  __builtin_amdgcn_s_setprio(1);                                              \
  _Pragma("unroll") for (int kk_ = 0; kk_ < 2; ++kk_)                         \
  _Pragma("unroll") for (int i_ = 0; i_ < 2; ++i_)                            \
  _Pragma("unroll") for (int ni_ = 0; ni_ < 4; ++ni_)                         \
    acc[(MI0)+i_][ni_] = __builtin_amdgcn_mfma_f32_16x16x32_bf16(             \
        AF[i_][kk_], BF[ni_][kk_], acc[(MI0)+i_][ni_], 0, 0, 0);              \
  __builtin_amdgcn_s_setprio(0);

#define STAGE(T1)                                                             \
  { const int kof_ = (T1) * GBK;                                              \
    char* dA_ = ldsA + ((T1) & 1) * TILE_BYTES;                               \
    char* dB_ = ldsB + ((T1) & 1) * TILE_BYTES;                               \
    _Pragma("unroll") for (int l_ = 0; l_ < 4; ++l_) {                        \
      gl_lds16(sA + (size_t)l_ * (64 * MM) + kof_, dA_ + dstb + l_ * 8192);   \
      gl_lds16(sB + (size_t)l_ * (64 * MM) + kof_, dB_ + dstb + l_ * 8192);   \
    } }

#define TILE_FULL(T, BFC, BFN, AF0C, AF0N)                                    \
  {                                                                           \
    const int t_ = (T);                                                       \
    const char* Ab_  = ldsA + (t_ & 1) * TILE_BYTES;                          \
    const char* AbN_ = ldsA + ((t_ + 1) & 1) * TILE_BYTES;                    \
    const char* BbN_ = ldsB + ((t_ + 1) & 1) * TILE_BYTES;                    \
    __builtin_amdgcn_s_barrier();                                             \
    STAGE(t_ + 1);                                                            \
    bf16x8 af1[2][2], af2[2][2], af3[2][2];                                   \
    RD_A(af1, Ab_, 1);                                                        \
    LGKM(4);                                                                  \
    MFMA_PH(AF0C, BFC, 0);                                                    \
    RD_A(af2, Ab_, 2);                                                        \
    LGKM(4);                                                                  \
    MFMA_PH(af1, BFC, 2);                                                     \
    RD_A(af3, Ab_, 3);                                                        \
    VMC0();                                                                   \
    __builtin_amdgcn_s_barrier();                                             \
    RD_B(BFN, BbN_);                                                          \
    LGKM(12);                                                                 \
    MFMA_PH(af2, BFC, 4);                                                     \
    RD_A(AF0N, AbN_, 0);                                                      \
    LGKM(12);                                                                 \
    MFMA_PH(af3, BFC, 6);                                                     \
  }

__global__ __launch_bounds__(512, 2) void gemm8(
    const unsigned short* __restrict__ xb,
    const unsigned short* __restrict__ wb,
    const float* __restrict__ bias,
    float* __restrict__ C)
{
  __shared__ __align__(16) unsigned short As[2 * GBM * GBK];  // 64 KiB
  __shared__ __align__(16) unsigned short Bs[2 * GBN * GBK];  // 64 KiB
  char* ldsA = (char*)As;
  char* ldsB = (char*)Bs;

  // grid = 512 = 32 (tm) x 16 (tn); 512 % 8 == 0 -> simple XCD swizzle
  int bid = blockIdx.x;
  int swz = (bid & 7) * 64 + (bid >> 3);
  int tn = swz & 15, tm = swz >> 4;
  const int trow0 = tm * GBM;
  const int tcol0 = tn * GBN;

  int tid  = threadIdx.x;
  int lane = tid & 63;
  int wid  = tid >> 6;
  int wr = wid >> 2, wc = wid & 3;   // wave coords: 2 x 4
  int lr = lane & 15;                // fragment row/col
  int lg = lane >> 4;                // k-group (8 bf16 = 16B)
  const int sw = (lr & 7) << 4;      // swizzle byte term
  const int arow0 = wr * 16384 + lr * 128;  // A: (wr*128+lr)*128
  const int brow0 = wc * 8192  + lr * 128;  // B: (wc*64+lr)*128

  // staging geometry: 4 granules/thread/operand; row r0+64*l, const col group
  const int r0   = tid >> 3;
  const int colg = (tid & 7) ^ (r0 & 7);
  const unsigned short* sA = xb + (size_t)(trow0 + r0) * MM + colg * 8;
  const unsigned short* sB = wb + (size_t)(tcol0 + r0) * MM + colg * 8;
  const int dstb = tid * 16;

  f32x4 acc[8][4];
  #pragma unroll
  for (int i = 0; i < 8; i++)
    #pragma unroll
    for (int j = 0; j < 4; j++) {
      f32x4 z = {0.f, 0.f, 0.f, 0.f};
      acc[i][j] = z;
    }

  // ---- prologue: stage tile 0, drain, read B_0 + af0_0 ----
  STAGE(0);
  VMC0();
  __builtin_amdgcn_s_barrier();

  bf16x8 bfA[4][2], bfB[4][2], af0A[2][2], af0B[2][2];
  RD_B(bfA, ldsB);
  RD_A(af0A, ldsA, 0);

  // ---- main loop: unroll x2 for static register rotation ----
  for (int tt = 0; tt < NT - 2; tt += 2) {
    TILE_FULL(tt,     bfA, bfB, af0A, af0B);
    TILE_FULL(tt + 1, bfB, bfA, af0B, af0A);
  }
  TILE_FULL(NT - 2, bfA, bfB, af0A, af0B);   // t = 62 (even)

  // ---- last tile (t = 63), peeled: no staging, no prefetch ----
  {
    const char* Ab_ = ldsA + ((NT - 1) & 1) * TILE_BYTES;
    __builtin_amdgcn_s_barrier();
    bf16x8 af1[2][2], af2[2][2], af3[2][2];
    RD_A(af1, Ab_, 1);
    LGKM(4);
    MFMA_PH(af0B, bfB, 0);
    RD_A(af2, Ab_, 2);
    LGKM(4);
    MFMA_PH(af1, bfB, 2);
    RD_A(af3, Ab_, 3);
    LGKM(4);
    MFMA_PH(af2, bfB, 4);
    LGKM(0);
    MFMA_PH(af3, bfB, 6);
  }

  // ---- epilogue: C/D layout col = lane&15, row = (lane>>4)*4 + reg ----
  #pragma unroll
  for (int ni = 0; ni < 4; ++ni) {
    int col = tcol0 + wc * 64 + ni * 16 + lr;
    float bi = bias[col];
    #pragma unroll
    for (int mi = 0; mi < 8; ++mi) {
      int rr0 = trow0 + wr * 128 + mi * 16 + lg * 4;
      #pragma unroll
      for (int qq = 0; qq < 4; ++qq)
        C[(size_t)(rr0 + qq) * NN + col] = acc[mi][ni][qq] + bi;
    }
  }
}

// ---------------------------------------------------------------------------
// Kernel 5b (fallback, ws too small for xb): m97-style 128x128 GEMM with
// inline f32->bf16 A-staging.
// ---------------------------------------------------------------------------
constexpr int BM = 128, BN = 128, BK = 64;

__global__ __launch_bounds__(256) void gemm_fb(
    const float* __restrict__ xf,
    const unsigned short* __restrict__ wb, const float* __restrict__ bias,
    float* __restrict__ C)
{
  __shared__ __align__(16) unsigned short As2[BM * BK];
  __shared__ __align__(16) unsigned short Bs2[BN * BK];

  int bid = blockIdx.x;
  int swz = (bid & 7) * 256 + (bid >> 3);
  int tn = swz & 31;
  int tm = swz >> 5;

  int tid  = threadIdx.x;
  int lane = tid & 63;
  int wid  = tid >> 6;
  int wr = wid >> 1, wc = wid & 1;
  int lr = lane & 15;
  int lg = lane >> 4;

  f32x4 acc[4][4];
  #pragma unroll
  for (int i = 0; i < 4; i++)
    #pragma unroll
    for (int j = 0; j < 4; j++) {
      f32x4 z = {0.f, 0.f, 0.f, 0.f};
      acc[i][j] = z;
    }

  int srow = tid >> 3;
  int scol = (tid & 7) * 8;
  const size_t a_base = (size_t)(tm * BM) * MM;
  const size_t b_base = (size_t)(tn * BN) * MM;

  for (int k0 = 0; k0 < MM; k0 += BK) {
    #pragma unroll
    for (int c = 0; c < 4; c++) {
      int row = c * 32 + srow;
      gl_lds16(wb + b_base + (size_t)row * MM + k0 + scol,
               (char*)Bs2 + (c * 256 + wid * 64) * 16);
    }
    #pragma unroll
    for (int c = 0; c < 4; c++) {
      int row = c * 32 + srow;
      const float* s = xf + a_base + (size_t)row * MM + k0 + scol;
      f32x4 v0 = *(const f32x4*)s;
      f32x4 v1 = *(const f32x4*)(s + 4);
      ushort8 p;
      p[0] = f2bf(v0.x); p[1] = f2bf(v0.y); p[2] = f2bf(v0.z); p[3] = f2bf(v0.w);
      p[4] = f2bf(v1.x); p[5] = f2bf(v1.y); p[6] = f2bf(v1.z); p[7] = f2bf(v1.w);
      *(ushort8*)&As2[(c * 256 + tid) * 8] = p;
    }
    __syncthreads();

    #pragma unroll
    for (int kk = 0; kk < 2; kk++) {
      bf16x8 a[4], b[4];
      #pragma unroll
      for (int i = 0; i < 4; i++) {
        a[i] = *(const bf16x8*)&As2[(wr * 64 + i * 16 + lr) * BK + kk * 32 + lg * 8];
        b[i] = *(const bf16x8*)&Bs2[(wc * 64 + i * 16 + lr) * BK + kk * 32 + lg * 8];
      }
      #pragma unroll
      for (int i = 0; i < 4; i++)
        #pragma unroll
        for (int j = 0; j < 4; j++)
          acc[i][j] = __builtin_amdgcn_mfma_f32_16x16x32_bf16(a[i], b[j], acc[i][j], 0, 0, 0);
    }
    __syncthreads();
  }

  int gn0 = tn * BN + wc * 64;
  int gt0 = tm * BM + wr * 64;
  #pragma unroll
  for (int j = 0; j < 4; j++) {
    int gn = gn0 + j * 16 + lr;
    float bi = bias[gn];
    #pragma unroll
    for (int i = 0; i < 4; i++) {
      int t0 = gt0 + i * 16 + lg * 4;
      #pragma unroll
      for (int q = 0; q < 4; q++)
        C[(size_t)(t0 + q) * NN + gn] = acc[i][j][q] + bi;
    }
  }
}

// ---------------------------------------------------------------------------
extern "C" void kernel_launch(void* const* d_in, const int* in_sizes, int n_in,
                              void* d_out, int out_size, void* d_ws, size_t ws_size,
                              hipStream_t stream)
{
  const float* x    = (const float*)d_in[0];
  const float* W    = (const float*)d_in[1];
  const float* bias = (const float*)d_in[2];
  const float* thL  = (const float*)d_in[3];
  const float* thR  = (const float*)d_in[4];
  const float* elm  = (const float*)d_in[5];
  const float* brn  = (const float*)d_in[6];
  const int*   prL  = (const int*)d_in[7];
  const int*   prR  = (const int*)d_in[8];
  float* out = (float*)d_out;

  char* ws = (char*)d_ws;
  unsigned short* Wb = (unsigned short*)ws;          // N*M bf16 = 33.5 MB
  size_t off = (size_t)NN * MM * 2;
  float* rowC = (float*)(ws + off); off += NN * 4;
  float* rowS = (float*)(ws + off); off += NN * 4;
  int*   rowP = (int*)  (ws + off); off += NN * 4;
  float* colC = (float*)(ws + off); off += MM * 4;
  float* colS = (float*)(ws + off); off += MM * 4;
  int*   colP = (int*)  (ws + off); off += MM * 4;
  unsigned short* xb = (unsigned short*)(ws + off);  // T*M bf16 = 67 MB
  bool use_xb = ws_size >= off + (size_t)T_N * MM * 2;

  init_maps <<<16, 256, 0, stream>>>(rowC, rowS, rowP, colC, colS, colP);
  build_maps<<< 8, 256, 0, stream>>>(thL, thR, prL, prR, rowC, rowS, rowP, colC, colS, colP);
  build_weff<<<NN, 256, 0, stream>>>(W, brn, elm, rowC, rowS, rowP, colC, colS, colP, Wb);

  if (use_xb) {
    conv_x<<<2048, 256, 0, stream>>>(x, xb);
    gemm8<<<512, 512, 0, stream>>>(xb, Wb, bias, out);
  } else {
    gemm_fb<<<2048, 256, 0, stream>>>(x, Wb, bias, out);
  }
}

// Round 5
// 325.437 us; speedup vs baseline: 1.2385x; 1.0894x over previous
//
#include <hip/hip_runtime.h>
#include <cstdint>
#include <cstddef>

// Problem constants
constexpr int T_N = 8192;   // rows of x / out
constexpr int MM  = 4096;   // K (cols of x, cols of W)
constexpr int NN  = 4096;   // rows of W / cols of out
constexpr int S_L = 2048;
constexpr int S_R = 2048;
constexpr float EPS_ = 1e-6f;

typedef float  f32x4  __attribute__((ext_vector_type(4)));
typedef __bf16 bf16x8 __attribute__((ext_vector_type(8)));
typedef unsigned short ushort8 __attribute__((ext_vector_type(8)));

__device__ __forceinline__ unsigned short f2bf(float f) {
  unsigned int u = __float_as_uint(f);
  u += 0x7FFFu + ((u >> 16) & 1u);   // round-to-nearest-even
  return (unsigned short)(u >> 16);
}

// ---------------------------------------------------------------------------
// Kernel 1: default maps (identity)
// ---------------------------------------------------------------------------
__global__ void init_maps(float* rowC, float* rowS, int* rowP,
                          float* colC, float* colS, int* colP) {
  int i = blockIdx.x * blockDim.x + threadIdx.x;
  if (i < NN) { rowC[i] = 1.f; rowS[i] = 0.f; rowP[i] = i; }
  if (i < MM) { colC[i] = 1.f; colS[i] = 0.f; colP[i] = i; }
}

// ---------------------------------------------------------------------------
// Kernel 2: per-index rotation maps from (pairs, theta).
// ---------------------------------------------------------------------------
__global__ void build_maps(const float* __restrict__ thL, const float* __restrict__ thR,
                           const int* __restrict__ prL, const int* __restrict__ prR,
                           float* rowC, float* rowS, int* rowP,
                           float* colC, float* colS, int* colP) {
  int s = blockIdx.x * blockDim.x + threadIdx.x;
  if (s < S_L) {
    int i = prL[2*s], j = prL[2*s+1];
    float c = cosf(thL[s]), sn = sinf(thL[s]);
    rowC[i] = c; rowS[i] = -sn; rowP[i] = j;
    rowC[j] = c; rowS[j] =  sn; rowP[j] = i;
  }
  if (s < S_R) {
    int i = prR[2*s], j = prR[2*s+1];
    float c = cosf(thR[s]), sn = sinf(thR[s]);
    colC[i] = c; colS[i] = -sn; colP[i] = j;
    colC[j] = c; colS[j] =  sn; colP[j] = i;
  }
}

// ---------------------------------------------------------------------------
// Kernel 3: build W_eff row-by-row, fused row-norm, emit bf16.
// ---------------------------------------------------------------------------
__global__ __launch_bounds__(256) void build_weff(
    const float* __restrict__ W, const float* __restrict__ brn, const float* __restrict__ elm,
    const float* __restrict__ rowC, const float* __restrict__ rowS, const int* __restrict__ rowP,
    const float* __restrict__ colC, const float* __restrict__ colS, const int* __restrict__ colP,
    unsigned short* __restrict__ Wb)
{
  __shared__ __align__(16) float rA[MM];
  __shared__ __align__(16) float rB[MM];
  __shared__ __align__(16) float rE[MM];
  __shared__ float red[4];

  int n   = blockIdx.x;
  int tid = threadIdx.x;
  int pn  = rowP[n];
  float cl = rowC[n], sl = rowS[n];
  const float* Wn = W + (size_t)n  * MM;
  const float* Wp = W + (size_t)pn * MM;

  for (int m = tid * 4; m < MM; m += 1024) {
    *(f32x4*)&rA[m] = *(const f32x4*)&Wn[m];
    *(f32x4*)&rB[m] = *(const f32x4*)&Wp[m];
  }
  __syncthreads();

  float ss = 0.f;
  for (int m = tid; m < MM; m += 256) {
    int p = colP[m];
    float c = colC[m], s = colS[m];
    float e = cl * (c * rA[m] + s * rA[p]) + sl * (c * rB[m] + s * rB[p]);
    rE[m] = e;
    ss += e * e;
  }
  #pragma unroll
  for (int o = 32; o; o >>= 1) ss += __shfl_xor(ss, o);
  int lane = tid & 63, wid = tid >> 6;
  if (lane == 0) red[wid] = ss;
  __syncthreads();
  float tot = red[0] + red[1] + red[2] + red[3];
  float scale = brn[n] * expf(elm[n]) / sqrtf(tot + EPS_);

  for (int m = tid * 8; m < MM; m += 2048) {
    ushort8 pkt;
    #pragma unroll
    for (int q = 0; q < 8; q++) pkt[q] = f2bf(rE[m + q] * scale);
    *(ushort8*)&Wb[(size_t)n * MM + m] = pkt;
  }
}

// ---------------------------------------------------------------------------
// Kernel 4: x (f32) -> bf16
// ---------------------------------------------------------------------------
__global__ __launch_bounds__(256) void conv_x(const float* __restrict__ x,
                                              unsigned short* __restrict__ xb) {
  const size_t total = (size_t)T_N * MM / 8;
  for (size_t i = (size_t)blockIdx.x * 256 + threadIdx.x; i < total; i += 2048ull * 256ull) {
    const float* s = x + i * 8;
    f32x4 v0 = *(const f32x4*)s;
    f32x4 v1 = *(const f32x4*)(s + 4);
    ushort8 p;
    p[0] = f2bf(v0.x); p[1] = f2bf(v0.y); p[2] = f2bf(v0.z); p[3] = f2bf(v0.w);
    p[4] = f2bf(v1.x); p[5] = f2bf(v1.y); p[6] = f2bf(v1.z); p[7] = f2bf(v1.w);
    *(ushort8*)(xb + i * 8) = p;
  }
}

// ---------------------------------------------------------------------------
// global->LDS async staging helper (16B, linear LDS dest)
// ---------------------------------------------------------------------------
typedef const __attribute__((address_space(1))) unsigned int* as1_u32p;
typedef __attribute__((address_space(3))) unsigned int* as3_u32p;

__device__ __forceinline__ void gl_lds16(const void* g, void* l) {
  __builtin_amdgcn_global_load_lds((as1_u32p)g, (as3_u32p)l, 16, 0, 0);
}

// ---------------------------------------------------------------------------
// Kernel 5a: 256x256 GEMM, BK=64, 8 waves (2Mx4N), per-wave 128x64, acc[8][4].
// Fully-counted single-barrier pipeline:
//   A: 3 LDS slots (96KB), staged 2 tiles ahead.  B: 2 slots (64KB), 1 ahead.
//   Per tile: [B01+af0 | af1+STAGE_B | STAGE_A] regions fenced by
//   sched_barrier(0); then LGKM(4) ladder interleaving one read-group with
//   one 8-MFMA cluster; LGKM(0); tail clusters; vmcnt(4); s_barrier.
//   vm FIFO at gate: [A(t+1), B(t+1), A(t+2)] -> vmcnt(4) retires A/B(t+1),
//   keeps A(t+2) in flight (never drains to 0 until the 2 tail tiles).
// Swizzle (verified r2): LDS[row][colu]=glob[row][colu^(row&7)] (16B units);
// read byte addr: row*128 + ((kk*64+lg*16) ^ ((lr&7)<<4)).  Conflict-free.
// ---------------------------------------------------------------------------
constexpr int GBM = 256, GBN = 256, GBK = 64;
constexpr int NTK = MM / GBK;              // 64 K-tiles
constexpr int ASLOT = GBM * GBK * 2;       // 32 KiB
constexpr int BSLOT = GBN * GBK * 2;       // 32 KiB

#define SB0() __builtin_amdgcn_sched_barrier(0)
#define LGKM(N) do { asm volatile("s_waitcnt lgkmcnt(" #N ")" ::: "memory"); \
                     SB0(); } while (0)

#define RD_BP(NI0, BB)                                                        \
  _Pragma("unroll") for (int n_ = 0; n_ < 2; ++n_)                            \
  _Pragma("unroll") for (int k_ = 0; k_ < 2; ++k_)                            \
    bf[(NI0) + n_][k_] = *(const bf16x8*)((BB) + brow0 + ((NI0) + n_) * 2048  \
                                           + ((k_ * 64 + lg * 16) ^ sw));

#define RD_AQ(DST, AB, Q)                                                     \
  _Pragma("unroll") for (int i_ = 0; i_ < 2; ++i_)                            \
  _Pragma("unroll") for (int k_ = 0; k_ < 2; ++k_)                            \
    DST[i_][k_] = *(const bf16x8*)((AB) + arow0 + ((Q) * 2 + i_) * 2048       \
                                    + ((k_ * 64 + lg * 16) ^ sw));

#define CL(AF, Q, H)                                                          \
  __builtin_amdgcn_s_setprio(1);                                              \
  _Pragma("unroll") for (int k_ = 0; k_ < 2; ++k_)                            \
  _Pragma("unroll") for (int i_ = 0; i_ < 2; ++i_)                            \
  _Pragma("unroll") for (int n_ = 0; n_ < 2; ++n_)                            \
    acc[(Q) * 2 + i_][(H) + n_] = __builtin_amdgcn_mfma_f32_16x16x32_bf16(    \
        AF[i_][k_], bf[(H) + n_][k_], acc[(Q) * 2 + i_][(H) + n_], 0, 0, 0);  \
  __builtin_amdgcn_s_setprio(0);

#define STAGE_A(KOF, SL)                                                      \
  _Pragma("unroll") for (int l_ = 0; l_ < 4; ++l_)                            \
    gl_lds16(sA + (size_t)l_ * (64 * MM) + (KOF),                             \
             ldsA + (SL) * ASLOT + dstb + l_ * 8192);
#define STAGE_B(KOF, SL)                                                      \
  _Pragma("unroll") for (int l_ = 0; l_ < 4; ++l_)                            \
    gl_lds16(sB + (size_t)l_ * (64 * MM) + (KOF),                             \
             ldsB + (SL) * BSLOT + dstb + l_ * 8192);

#define GATE4 do { asm volatile("s_waitcnt vmcnt(4)" ::: "memory");           \
                   __builtin_amdgcn_s_barrier(); } while (0)
#define GATE0 do { asm volatile("s_waitcnt vmcnt(0)" ::: "memory");           \
                   __builtin_amdgcn_s_barrier(); } while (0)
#define NOGATE do { } while (0)

#define TILE(KOF, RA, RB, WA, WB, DOB, DOA, GATE)                             \
  {                                                                           \
    const char* Ab_ = ldsA + (RA) * ASLOT;                                    \
    const char* Bb_ = ldsB + (RB) * BSLOT;                                    \
    bf16x8 bf[4][2], af0[2][2], af1[2][2], af2[2][2], af3[2][2];              \
    RD_BP(0, Bb_);                                                            \
    RD_AQ(af0, Ab_, 0);                                                       \
    SB0();                                                                    \
    RD_AQ(af1, Ab_, 1);                                                       \
    if (DOB) { STAGE_B((KOF) + GBK, WB); }                                    \
    SB0();                                                                    \
    if (DOA) { STAGE_A((KOF) + 2 * GBK, WA); }                                \
    LGKM(4);                                                                  \
    CL(af0, 0, 0);                       /* c00 */                            \
    RD_BP(2, Bb_);                                                            \
    LGKM(4);                                                                  \
    CL(af1, 1, 0);                       /* c10 */                            \
    RD_AQ(af2, Ab_, 2);                                                       \
    LGKM(4);                                                                  \
    CL(af0, 0, 2);                       /* c01 */                            \
    RD_AQ(af3, Ab_, 3);                                                       \
    LGKM(4);                                                                  \
    CL(af1, 1, 2);                       /* c11 */                            \
    CL(af2, 2, 0);                       /* c20 */                            \
    CL(af2, 2, 2);                       /* c21 */                            \
    LGKM(0);                                                                  \
    CL(af3, 3, 0);                       /* c30 */                            \
    CL(af3, 3, 2);                       /* c31 */                            \
    GATE;                                                                     \
  }

__global__ __launch_bounds__(512, 2) void gemm8(
    const unsigned short* __restrict__ xb,
    const unsigned short* __restrict__ wb,
    const float* __restrict__ bias,
    float* __restrict__ C)
{
  __shared__ __align__(16) unsigned short As[3 * GBM * GBK];  // 96 KiB
  __shared__ __align__(16) unsigned short Bs[2 * GBN * GBK];  // 64 KiB
  char* ldsA = (char*)As;
  char* ldsB = (char*)Bs;

  // grid = 512 = 32 (tm) x 16 (tn); 512 % 8 == 0 -> simple XCD swizzle
  int bid = blockIdx.x;
  int swz = (bid & 7) * 64 + (bid >> 3);
  int tn = swz & 15, tm = swz >> 4;
  const int trow0 = tm * GBM;
  const int tcol0 = tn * GBN;

  int tid  = threadIdx.x;
  int lane = tid & 63;
  int wid  = tid >> 6;
  int wr = wid >> 2, wc = wid & 3;   // wave coords: 2 x 4
  int lr = lane & 15;                // fragment row/col
  int lg = lane >> 4;                // k-group (8 bf16 = 16B)
  const int sw = (lr & 7) << 4;      // swizzle byte term
  const int arow0 = wr * 16384 + lr * 128;  // A: (wr*128+lr)*128
  const int brow0 = wc * 8192  + lr * 128;  // B: (wc*64+lr)*128

  // staging geometry: 4 granules/thread/operand; row r0+64*l, const col group
  const int r0   = tid >> 3;
  const int colg = (tid & 7) ^ (r0 & 7);
  const unsigned short* sA = xb + (size_t)(trow0 + r0) * MM + colg * 8;
  const unsigned short* sB = wb + (size_t)(tcol0 + r0) * MM + colg * 8;
  const int dstb = tid * 16;

  f32x4 acc[8][4];
  #pragma unroll
  for (int i = 0; i < 8; i++)
    #pragma unroll
    for (int j = 0; j < 4; j++) {
      f32x4 z = {0.f, 0.f, 0.f, 0.f};
      acc[i][j] = z;
    }

  // ---- prologue: B(0),A(0) | B(1),A(1),A(2); gate {B0,A0}; barrier ----
  STAGE_B(0, 0);
  STAGE_A(0, 0);
  SB0();
  STAGE_B(GBK, 1);
  STAGE_A(GBK, 1);
  STAGE_A(2 * GBK, 2);
  asm volatile("s_waitcnt vmcnt(12)" ::: "memory");
  __builtin_amdgcn_s_barrier();

  // ---- main loop: tiles 0..59, slots period 6 = lcm(3,2) ----
  int kof = 0;
  #pragma unroll 1
  for (int tb = 0; tb < NTK - 4; tb += 6) {
    TILE(kof      , 0, 0, 2, 1, 1, 1, GATE4);
    TILE(kof +  64, 1, 1, 0, 0, 1, 1, GATE4);
    TILE(kof + 128, 2, 0, 1, 1, 1, 1, GATE4);
    TILE(kof + 192, 0, 1, 2, 0, 1, 1, GATE4);
    TILE(kof + 256, 1, 0, 0, 1, 1, 1, GATE4);
    TILE(kof + 320, 2, 1, 1, 0, 1, 1, GATE4);
    kof += 384;
  }
  // ---- tail tiles 60..63 ----
  TILE(kof      , 0, 0, 2, 1, 1, 1, GATE4);   // t=60: B61->s1, A62->s2
  TILE(kof +  64, 1, 1, 0, 0, 1, 1, GATE4);   // t=61: B62->s0, A63->s0
  TILE(kof + 128, 2, 0, 0, 1, 1, 0, GATE0);   // t=62: B63->s1 only
  TILE(kof + 192, 0, 1, 0, 0, 0, 0, NOGATE);  // t=63

  // ---- epilogue: C/D layout col = lane&15, row = (lane>>4)*4 + reg ----
  #pragma unroll
  for (int ni = 0; ni < 4; ++ni) {
    int col = tcol0 + wc * 64 + ni * 16 + lr;
    float bi = bias[col];
    #pragma unroll
    for (int mi = 0; mi < 8; ++mi) {
      int rr0 = trow0 + wr * 128 + mi * 16 + lg * 4;
      #pragma unroll
      for (int qq = 0; qq < 4; ++qq)
        C[(size_t)(rr0 + qq) * NN + col] = acc[mi][ni][qq] + bi;
    }
  }
}

// ---------------------------------------------------------------------------
// Kernel 5b (fallback, ws too small for xb): m97-style 128x128 GEMM with
// inline f32->bf16 A-staging.
// ---------------------------------------------------------------------------
constexpr int BM = 128, BN = 128, BK = 64;

__global__ __launch_bounds__(256) void gemm_fb(
    const float* __restrict__ xf,
    const unsigned short* __restrict__ wb, const float* __restrict__ bias,
    float* __restrict__ C)
{
  __shared__ __align__(16) unsigned short As2[BM * BK];
  __shared__ __align__(16) unsigned short Bs2[BN * BK];

  int bid = blockIdx.x;
  int swz = (bid & 7) * 256 + (bid >> 3);
  int tn = swz & 31;
  int tm = swz >> 5;

  int tid  = threadIdx.x;
  int lane = tid & 63;
  int wid  = tid >> 6;
  int wr = wid >> 1, wc = wid & 1;
  int lr = lane & 15;
  int lg = lane >> 4;

  f32x4 acc[4][4];
  #pragma unroll
  for (int i = 0; i < 4; i++)
    #pragma unroll
    for (int j = 0; j < 4; j++) {
      f32x4 z = {0.f, 0.f, 0.f, 0.f};
      acc[i][j] = z;
    }

  int srow = tid >> 3;
  int scol = (tid & 7) * 8;
  const size_t a_base = (size_t)(tm * BM) * MM;
  const size_t b_base = (size_t)(tn * BN) * MM;

  for (int k0 = 0; k0 < MM; k0 += BK) {
    #pragma unroll
    for (int c = 0; c < 4; c++) {
      int row = c * 32 + srow;
      gl_lds16(wb + b_base + (size_t)row * MM + k0 + scol,
               (char*)Bs2 + (c * 256 + wid * 64) * 16);
    }
    #pragma unroll
    for (int c = 0; c < 4; c++) {
      int row = c * 32 + srow;
      const float* s = xf + a_base + (size_t)row * MM + k0 + scol;
      f32x4 v0 = *(const f32x4*)s;
      f32x4 v1 = *(const f32x4*)(s + 4);
      ushort8 p;
      p[0] = f2bf(v0.x); p[1] = f2bf(v0.y); p[2] = f2bf(v0.z); p[3] = f2bf(v0.w);
      p[4] = f2bf(v1.x); p[5] = f2bf(v1.y); p[6] = f2bf(v1.z); p[7] = f2bf(v1.w);
      *(ushort8*)&As2[(c * 256 + tid) * 8] = p;
    }
    __syncthreads();

    #pragma unroll
    for (int kk = 0; kk < 2; kk++) {
      bf16x8 a[4], b[4];
      #pragma unroll
      for (int i = 0; i < 4; i++) {
        a[i] = *(const bf16x8*)&As2[(wr * 64 + i * 16 + lr) * BK + kk * 32 + lg * 8];
        b[i] = *(const bf16x8*)&Bs2[(wc * 64 + i * 16 + lr) * BK + kk * 32 + lg * 8];
      }
      #pragma unroll
      for (int i = 0; i < 4; i++)
        #pragma unroll
        for (int j = 0; j < 4; j++)
          acc[i][j] = __builtin_amdgcn_mfma_f32_16x16x32_bf16(a[i], b[j], acc[i][j], 0, 0, 0);
    }
    __syncthreads();
  }

  int gn0 = tn * BN + wc * 64;
  int gt0 = tm * BM + wr * 64;
  #pragma unroll
  for (int j = 0; j < 4; j++) {
    int gn = gn0 + j * 16 + lr;
    float bi = bias[gn];
    #pragma unroll
    for (int i = 0; i < 4; i++) {
      int t0 = gt0 + i * 16 + lg * 4;
      #pragma unroll
      for (int q = 0; q < 4; q++)
        C[(size_t)(t0 + q) * NN + gn] = acc[i][j][q] + bi;
    }
  }
}

// ---------------------------------------------------------------------------
extern "C" void kernel_launch(void* const* d_in, const int* in_sizes, int n_in,
                              void* d_out, int out_size, void* d_ws, size_t ws_size,
                              hipStream_t stream)
{
  const float* x    = (const float*)d_in[0];
  const float* W    = (const float*)d_in[1];
  const float* bias = (const float*)d_in[2];
  const float* thL  = (const float*)d_in[3];
  const float* thR  = (const float*)d_in[4];
  const float* elm  = (const float*)d_in[5];
  const float* brn  = (const float*)d_in[6];
  const int*   prL  = (const int*)d_in[7];
  const int*   prR  = (const int*)d_in[8];
  float* out = (float*)d_out;

  char* ws = (char*)d_ws;
  unsigned short* Wb = (unsigned short*)ws;          // N*M bf16 = 33.5 MB
  size_t off = (size_t)NN * MM * 2;
  float* rowC = (float*)(ws + off); off += NN * 4;
  float* rowS = (float*)(ws + off); off += NN * 4;
  int*   rowP = (int*)  (ws + off); off += NN * 4;
  float* colC = (float*)(ws + off); off += MM * 4;
  float* colS = (float*)(ws + off); off += MM * 4;
  int*   colP = (int*)  (ws + off); off += MM * 4;
  unsigned short* xb = (unsigned short*)(ws + off);  // T*M bf16 = 67 MB
  bool use_xb = ws_size >= off + (size_t)T_N * MM * 2;

  init_maps <<<16, 256, 0, stream>>>(rowC, rowS, rowP, colC, colS, colP);
  build_maps<<< 8, 256, 0, stream>>>(thL, thR, prL, prR, rowC, rowS, rowP, colC, colS, colP);
  build_weff<<<NN, 256, 0, stream>>>(W, brn, elm, rowC, rowS, rowP, colC, colS, colP, Wb);

  if (use_xb) {
    conv_x<<<2048, 256, 0, stream>>>(x, xb);
    gemm8<<<512, 512, 0, stream>>>(xb, Wb, bias, out);
  } else {
    gemm_fb<<<2048, 256, 0, stream>>>(x, Wb, bias, out);
  }
}